// Round 4
// baseline (64.571 us; speedup 1.0000x reference)
//
#include <hip/hip_runtime.h>

// x: (B=8, C=64, H=56, W=56) fp32; out: (B,C,49,3136) fp32
// out[b,c,(i*7+j),h*56+w] = x[b,c,h,w] - x[b,c, refl(h+i-3), refl(w+j-3)]
#define HH 56
#define WW 56
#define HWOUT (HH * WW)          // 3136
#define NBC (8 * 64)             // 512 images
#define NBLK (NBC * 7)           // 3584 blocks; block = (bc, di)
#define NXCD 8
#define CPX (NBLK / NXCD)        // 448 blocks per XCD chunk

typedef float f32x4 __attribute__((ext_vector_type(4)));  // native vec4 (works with nontemporal builtins)

// Single-bounce reflection, valid for t in [-3, 58]
__device__ __forceinline__ int refl(int t) {
    t = (t < 0) ? -t : t;
    return (t >= HH) ? (2 * HH - 2 - t) : t;
}

__global__ __launch_bounds__(256) void sub_kernel(const float* __restrict__ x,
                                                  float* __restrict__ out) {
    // XCD-aware swizzle: HW dispatches bid round-robin over 8 XCDs; remap so
    // XCD k gets the contiguous original-block range [k*448,(k+1)*448) =
    // bc in [k*64,(k+1)*64). Each image then lives in exactly one XCD's L2.
    const int bid = blockIdx.x;
    const int blk = (bid % NXCD) * CPX + bid / NXCD;

    const int di = blk % 7;                  // row-offset index 0..6 (offset di-3)
    const int bc = blk / 7;

    const float* __restrict__ img = x + (size_t)bc * HWOUT;
    float* __restrict__ oplane0 = out + ((size_t)bc * 49 + (size_t)di * 7) * HWOUT;

    for (int q = threadIdx.x; q < HWOUT / 4; q += 256) {
        const int e = q * 4;                 // 16B-aligned element offset
        const int h = e / WW;
        const int w = e - h * WW;            // 0,4,...,52

        const float* __restrict__ crow = img + h * WW;
        const float* __restrict__ nrow = img + refl(h + di - 3) * WW;

        const f32x4 cen = *reinterpret_cast<const f32x4*>(crow + w);

        // wnd[idx] corresponds to nrow[w - 4 + idx]; idx 1..10 used.
        float wnd[12];
        {   // lo: nrow[w-4 .. w-1]; for w==0 load a safe dummy (patched below)
            const f32x4 lo = *reinterpret_cast<const f32x4*>(nrow + (w == 0 ? 0 : w - 4));
            wnd[0] = lo.x; wnd[1] = lo.y; wnd[2] = lo.z; wnd[3] = lo.w;
        }
        {   // mid: nrow[w .. w+3]
            const f32x4 mid = *reinterpret_cast<const f32x4*>(nrow + w);
            wnd[4] = mid.x; wnd[5] = mid.y; wnd[6] = mid.z; wnd[7] = mid.w;
        }
        {   // hi: nrow[w+4 .. w+7]; for w==52 load a safe dummy (patched below)
            const f32x4 hi = *reinterpret_cast<const f32x4*>(nrow + (w == 52 ? 48 : w + 4));
            wnd[8] = hi.x; wnd[9] = hi.y; wnd[10] = hi.z; wnd[11] = hi.w;
        }
        if (w == 0) {       // nrow[-3,-2,-1] -> nrow[3,2,1]
            wnd[1] = nrow[3]; wnd[2] = nrow[2]; wnd[3] = nrow[1];
        }
        if (w == 52) {      // nrow[56,57,58] -> nrow[54,53,52]
            wnd[8] = nrow[54]; wnd[9] = nrow[53]; wnd[10] = nrow[52];
        }

        float* __restrict__ op = oplane0 + e;
        #pragma unroll
        for (int djj = 0; djj < 7; ++djj) {  // dj = djj - 3; all wnd indices static
            f32x4 r;
            r.x = cen.x - wnd[djj + 1];
            r.y = cen.y - wnd[djj + 2];
            r.z = cen.z - wnd[djj + 3];
            r.w = cen.w - wnd[djj + 4];
            // Nontemporal: output is write-once/never-read — don't pollute L2
            // (protects the cached input images).
            __builtin_nontemporal_store(r, reinterpret_cast<f32x4*>(op + (size_t)djj * HWOUT));
        }
    }
}

extern "C" void kernel_launch(void* const* d_in, const int* in_sizes, int n_in,
                              void* d_out, int out_size, void* d_ws, size_t ws_size,
                              hipStream_t stream) {
    const float* x = (const float*)d_in[0];
    float* out = (float*)d_out;
    sub_kernel<<<dim3(NBLK), dim3(256), 0, stream>>>(x, out);
}

// Round 5
// 60.882 us; speedup vs baseline: 1.0606x; 1.0606x over previous
//
#include <hip/hip_runtime.h>

// x: (B=8, C=64, H=56, W=56) fp32; out: (B,C,49,3136) fp32
// out[b,c,(i*7+j),h*56+w] = x[b,c,h,w] - x[b,c, refl(h+i-3), refl(w+j-3)]
#define HH 56
#define WW 56
#define HWOUT (HH * WW)          // 3136
#define NBC (8 * 64)             // 512 images
#define NBLK (NBC * 7)           // 3584 blocks; block = (bc, di)
#define NXCD 8
#define CPX (NBLK / NXCD)        // 448 blocks per XCD chunk

typedef float f32x4 __attribute__((ext_vector_type(4)));

// Single-bounce reflection, valid for t in [-3, 58]
__device__ __forceinline__ int refl(int t) {
    t = (t < 0) ? -t : t;
    return (t >= HH) ? (2 * HH - 2 - t) : t;
}

__global__ __launch_bounds__(256) void sub_kernel(const float* __restrict__ x,
                                                  float* __restrict__ out) {
    // XCD-aware swizzle: XCD k gets original-block range [k*448,(k+1)*448) =
    // bc in [k*64,(k+1)*64) -> each image L2-resident on exactly one XCD.
    const int bid = blockIdx.x;
    const int blk = (bid % NXCD) * CPX + bid / NXCD;

    const int di = blk % 7;                  // row-offset index 0..6 (offset di-3)
    const int bc = blk / 7;

    const float* __restrict__ img = x + (size_t)bc * HWOUT;
    float* __restrict__ oplane0 = out + ((size_t)bc * 49 + (size_t)di * 7) * HWOUT;

    for (int q = threadIdx.x; q < HWOUT / 4; q += 256) {
        const int e = q * 4;                 // 16B-aligned element offset
        const int h = e / WW;
        const int w = e - h * WW;            // 0,4,...,52

        const float* __restrict__ crow = img + h * WW;
        const float* __restrict__ nrow = img + refl(h + di - 3) * WW;

        const f32x4 cen = *reinterpret_cast<const f32x4*>(crow + w);

        // wnd[idx] corresponds to nrow[w - 4 + idx]; idx 1..10 used.
        float wnd[12];
        {   // lo: nrow[w-4 .. w-1]; for w==0 load a safe dummy (patched below)
            const f32x4 lo = *reinterpret_cast<const f32x4*>(nrow + (w == 0 ? 0 : w - 4));
            wnd[0] = lo.x; wnd[1] = lo.y; wnd[2] = lo.z; wnd[3] = lo.w;
        }
        {   // mid: nrow[w .. w+3]
            const f32x4 mid = *reinterpret_cast<const f32x4*>(nrow + w);
            wnd[4] = mid.x; wnd[5] = mid.y; wnd[6] = mid.z; wnd[7] = mid.w;
        }
        {   // hi: nrow[w+4 .. w+7]; for w==52 load a safe dummy (patched below)
            const f32x4 hi = *reinterpret_cast<const f32x4*>(nrow + (w == 52 ? 48 : w + 4));
            wnd[8] = hi.x; wnd[9] = hi.y; wnd[10] = hi.z; wnd[11] = hi.w;
        }
        if (w == 0) {       // nrow[-3,-2,-1] -> nrow[3,2,1]
            wnd[1] = nrow[3]; wnd[2] = nrow[2]; wnd[3] = nrow[1];
        }
        if (w == 52) {      // nrow[56,57,58] -> nrow[54,53,52]
            wnd[8] = nrow[54]; wnd[9] = nrow[53]; wnd[10] = nrow[52];
        }

        float* __restrict__ op = oplane0 + e;
        #pragma unroll
        for (int djj = 0; djj < 7; ++djj) {  // dj = djj - 3; all wnd indices static
            f32x4 r;
            r.x = cen.x - wnd[djj + 1];
            r.y = cen.y - wnd[djj + 2];
            r.z = cen.z - wnd[djj + 3];
            r.w = cen.w - wnd[djj + 4];
            *reinterpret_cast<f32x4*>(op + (size_t)djj * HWOUT) = r;
        }
    }
}

extern "C" void kernel_launch(void* const* d_in, const int* in_sizes, int n_in,
                              void* d_out, int out_size, void* d_ws, size_t ws_size,
                              hipStream_t stream) {
    const float* x = (const float*)d_in[0];
    float* out = (float*)d_out;
    sub_kernel<<<dim3(NBLK), dim3(256), 0, stream>>>(x, out);
}

// Round 6
// 57.601 us; speedup vs baseline: 1.1210x; 1.0570x over previous
//
#include <hip/hip_runtime.h>

// x: (B=8, C=64, H=56, W=56) fp32; out: (B,C,49,3136) fp32
// out[b,c,(i*7+j),h*56+w] = x[b,c,h,w] - x[b,c, refl(h+i-3), refl(w+j-3)]
#define HH 56
#define WW 56
#define HWOUT (HH * WW)          // 3136
#define NBLK (8 * 64 * 7)        // 3584 blocks; block = (bc, di)

typedef float f32x4 __attribute__((ext_vector_type(4)));

// Single-bounce reflection, valid for t in [-3, 58]
__device__ __forceinline__ int refl(int t) {
    t = (t < 0) ? -t : t;
    return (t >= HH) ? (2 * HH - 2 - t) : t;
}

// Issue the 4 vector loads for chunk q (branch-free clamped addresses).
__device__ __forceinline__ void load_win(const float* __restrict__ img, int di, int q,
                                         f32x4& cen, f32x4& lo, f32x4& mid, f32x4& hi,
                                         int& w_out) {
    const int e = q * 4;
    const int h = e / WW;
    const int w = e - h * WW;                 // 0,4,...,52
    const float* crow = img + h * WW;
    const float* nrow = img + refl(h + di - 3) * WW;
    cen = *reinterpret_cast<const f32x4*>(crow + w);
    lo  = *reinterpret_cast<const f32x4*>(nrow + (w == 0 ? 0 : w - 4));    // dummy at w==0
    mid = *reinterpret_cast<const f32x4*>(nrow + w);
    hi  = *reinterpret_cast<const f32x4*>(nrow + (w == 52 ? 48 : w + 4));  // dummy at w==52
    w_out = w;
}

// Consume one chunk: register-only edge fixups (cndmask), 28 subs, 7 stores.
__device__ __forceinline__ void finish(float* __restrict__ oplane0, int q, int w,
                                       f32x4 cen, f32x4 lo, f32x4 mid, f32x4 hi) {
    // wnd[idx] = nrow[w-4+idx] after reflection; idx 1..10 used.
    float wnd[12];
    wnd[0] = lo.x;  wnd[1] = lo.y;  wnd[2] = lo.z;  wnd[3] = lo.w;
    wnd[4] = mid.x; wnd[5] = mid.y; wnd[6] = mid.z; wnd[7] = mid.w;
    wnd[8] = hi.x;  wnd[9] = hi.y;  wnd[10] = hi.z; wnd[11] = hi.w;
    // w==0: nrow[-3,-2,-1] -> nrow[3,2,1] = mid.w, mid.z, mid.y  (register selects only)
    if (w == 0)  { wnd[1] = mid.w; wnd[2] = mid.z; wnd[3] = mid.y; }
    // w==52: nrow[56,57,58] -> nrow[54,53,52] = mid.z, mid.y, mid.x
    if (w == 52) { wnd[8] = mid.z; wnd[9] = mid.y; wnd[10] = mid.x; }

    float* __restrict__ op = oplane0 + q * 4;
    #pragma unroll
    for (int djj = 0; djj < 7; ++djj) {
        f32x4 r;
        r.x = cen.x - wnd[djj + 1];
        r.y = cen.y - wnd[djj + 2];
        r.z = cen.z - wnd[djj + 3];
        r.w = cen.w - wnd[djj + 4];
        *reinterpret_cast<f32x4*>(op + (size_t)djj * HWOUT) = r;
    }
}

__global__ __launch_bounds__(256) void sub_kernel(const float* __restrict__ x,
                                                  float* __restrict__ out) {
    const int blk = blockIdx.x;
    const int di = blk % 7;
    const int bc = blk / 7;
    const int tid = threadIdx.x;

    const float* __restrict__ img = x + (size_t)bc * HWOUT;
    float* __restrict__ oplane0 = out + ((size_t)bc * 49 + (size_t)di * 7) * HWOUT;

    // 784 chunks of f32x4; 256 threads -> 3 uniform iters + 16-thread tail.
    // Software pipeline: next iter's loads are issued BEFORE current iter's
    // stores, so s_waitcnt for load data never has to drain prior stores.
    f32x4 c0, l0, m0, h0; int w0;
    f32x4 c1, l1, m1, h1; int w1;
    f32x4 c2, l2, m2, h2; int w2;
    f32x4 c3, l3, m3, h3; int w3;
    const bool tail = (tid < 784 - 768);

    load_win(img, di, tid,       c0, l0, m0, h0, w0);
    load_win(img, di, tid + 256, c1, l1, m1, h1, w1);
    finish(oplane0, tid, w0, c0, l0, m0, h0);
    load_win(img, di, tid + 512, c2, l2, m2, h2, w2);
    finish(oplane0, tid + 256, w1, c1, l1, m1, h1);
    if (tail) load_win(img, di, tid + 768, c3, l3, m3, h3, w3);
    finish(oplane0, tid + 512, w2, c2, l2, m2, h2);
    if (tail) finish(oplane0, tid + 768, w3, c3, l3, m3, h3);
}

extern "C" void kernel_launch(void* const* d_in, const int* in_sizes, int n_in,
                              void* d_out, int out_size, void* d_ws, size_t ws_size,
                              hipStream_t stream) {
    const float* x = (const float*)d_in[0];
    float* out = (float*)d_out;
    sub_kernel<<<dim3(NBLK), dim3(256), 0, stream>>>(x, out);
}